// Round 3
// baseline (11634.209 us; speedup 1.0000x reference)
//
#include <hip/hip_runtime.h>

// B=16, T=256, IN=256, H=1024, L=4, 4 gates -> 4H=4096.
// R6 = proven R3 structure (4x pre_gemm + 4x single-layer cooperative scan,
// identical MFMA numerics) with the sync protocol rebuilt for latency:
//   - 2-level atomic counter tree  ->  per-producer flag words flags[t][wg]
//     (producer: drain + plain agent store, NO atomic RTT on critical path)
//   - tid0-spin + syncthreads release  ->  all 4 waves poll all 256 flags
//     (lane i watches flags[t-1][4i..4i+3], __all ballot), removing one
//     __syncthreads per step. Safe: a wave passes poll(t) only after its own
//     wave-0 set flag(t), which happens after wave-0's red[] reads.
//   - bounded spin (8k iters ~ 3ms/step worst case): any protocol bug
//     degrades to a measurable wrong answer, never a container-killing hang.
//
// ws (floats): pre 16,777,216 | seqA 4,194,304 | seqB 4,194,304
//              | hhi 4,194,304 u16 | hlo 4,194,304 u16
//              | flags 4 layers x 256 t x 256 wg ints (1 MB)   (~113.1 MB)

typedef float f32x4 __attribute__((ext_vector_type(4)));
typedef short bf16x8 __attribute__((ext_vector_type(8)));

__device__ __forceinline__ unsigned short f2bf_rn(float x) {
    unsigned int u = __float_as_uint(x);
    u += 0x7FFFu + ((u >> 16) & 1u);          // round-to-nearest-even
    return (unsigned short)(u >> 16);
}
__device__ __forceinline__ float bf2f(unsigned short s) {
    return __uint_as_float(((unsigned int)s) << 16);
}
__device__ __forceinline__ float sigmoidf_(float x) { return 1.0f / (1.0f + __expf(-x)); }
__device__ __forceinline__ float tanhf_(float x) {
    float e = __expf(2.0f * x);
    return 1.0f - 2.0f / (e + 1.0f);
}

// ---------------------------------------------------------------------------
// pre[t][b][g*1024+j] = sum_k inp[b*T+t][k] * W[g][k][j] + bias[g*1024+j]
// fp32, 128x128 tile, BK=16, 256 threads, 8x8 micro-tile. (unchanged)
// ---------------------------------------------------------------------------
__global__ __launch_bounds__(256)
void pre_gemm(const float* __restrict__ A, const float* __restrict__ W,
              const float* __restrict__ bias, float* __restrict__ out, int K)
{
    __shared__ float As[16][132];   // [k][m]
    __shared__ float Bs[16][132];   // [k][n]

    const int tid = threadIdx.x;
    const int m0 = blockIdx.y << 7;
    const int n0 = blockIdx.x << 7;
    const int g  = n0 >> 10;
    const int jb = n0 & 1023;
    const float* Wg = W + (size_t)g * K * 1024 + jb;

    const int tx = tid & 15;
    const int ty = tid >> 4;
    const int alk = tid & 15;
    const int alm = tid >> 4;
    const int bln = tid & 127;
    const int blkk = tid >> 7;

    float acc[8][8];
#pragma unroll
    for (int i = 0; i < 8; ++i)
#pragma unroll
        for (int j = 0; j < 8; ++j) acc[i][j] = 0.f;

    for (int k0 = 0; k0 < K; k0 += 16) {
        __syncthreads();
#pragma unroll
        for (int r = 0; r < 8; ++r) {
            int m = alm + (r << 4);
            As[alk][m] = A[(size_t)(m0 + m) * K + (k0 + alk)];
        }
#pragma unroll
        for (int r = 0; r < 8; ++r) {
            int kk = blkk + (r << 1);
            Bs[kk][bln] = Wg[(size_t)(k0 + kk) * 1024 + bln];
        }
        __syncthreads();
#pragma unroll
        for (int k = 0; k < 16; ++k) {
            float a[8], bb[8];
            *(f32x4*)&a[0]  = *(const f32x4*)&As[k][ty << 2];
            *(f32x4*)&a[4]  = *(const f32x4*)&As[k][64 + (ty << 2)];
            *(f32x4*)&bb[0] = *(const f32x4*)&Bs[k][tx << 2];
            *(f32x4*)&bb[4] = *(const f32x4*)&Bs[k][64 + (tx << 2)];
#pragma unroll
            for (int i = 0; i < 8; ++i)
#pragma unroll
                for (int j = 0; j < 8; ++j)
                    acc[i][j] = fmaf(a[i], bb[j], acc[i][j]);
        }
    }

    float bj[8];
#pragma unroll
    for (int j = 0; j < 8; ++j) {
        int nloc = (j < 4) ? ((tx << 2) + j) : (64 + (tx << 2) + (j - 4));
        bj[j] = bias[n0 + nloc];
    }
#pragma unroll
    for (int i = 0; i < 8; ++i) {
        int mloc = (i < 4) ? ((ty << 2) + i) : (64 + (ty << 2) + (i - 4));
        int m = m0 + mloc;
        int bidx = m >> 8;
        int tt   = m & 255;
        float* orow = out + ((size_t)((tt << 4) + bidx) << 12) + n0;
#pragma unroll
        for (int j = 0; j < 8; ++j) {
            int nloc = (j < 4) ? ((tx << 2) + j) : (64 + (tx << 2) + (j - 4));
            orow[nloc] = acc[i][j] + bj[j];
        }
    }
}

// ---------------------------------------------------------------------------
// Persistent cooperative LSTM scan, one layer. 256 wgs x 256 threads.
// Producer (wave 0): gates -> h stores (agent write-through) -> s_waitcnt(0)
// -> plain agent store flags[t][wg]=1.
// Consumers (all 4 waves): lane-parallel poll of all 256 flags[t-1][*];
// flag seen ==> producer's h already at the coherence point; consumer L1/L2
// cannot hold stale copies (fresh address per t + kernel-start acquire).
// ---------------------------------------------------------------------------
__global__ __launch_bounds__(256)
void lstm_scan(const float* __restrict__ pre,    // [T][B][4096]
               const float* __restrict__ Wh,     // [4][1024][1024] this layer
               float* __restrict__ seq_out,      // [B][T][1024]
               unsigned short* __restrict__ hhi, // [T][16][1024] bf16 hi plane
               unsigned short* __restrict__ hlo, // [T][16][1024] bf16 lo plane
               int* __restrict__ flags,          // [256 t][256 wg]
               float* __restrict__ final_out,    // [16][1024]
               int is_last)
{
    const int wg   = blockIdx.x;
    const int tid  = threadIdx.x;
    const int wv   = tid >> 6;        // wave 0..3 owns k-range [wv*256, +256)
    const int lane = tid & 63;
    const int bc   = lane & 15;       // A-frag m (=batch) / B-frag n (=gate col)
    const int quad = lane >> 4;

    __shared__ float red[4][64][4];   // cross-wave C reduction
    __shared__ float gsh[16][17];     // gate exchange [b][g*4+jl]

    // ---- one-time: load Wh slice, 3-term bf16 split into registers ----
    const int g   = bc >> 2;
    const int col = (wg << 2) + (bc & 3);
    bf16x8 Whi[8], Wmi[8], Wlo[8];
#pragma unroll
    for (int ck = 0; ck < 8; ++ck) {
#pragma unroll
        for (int j = 0; j < 8; ++j) {
            int k = (wv << 8) + (ck << 5) + (quad << 3) + j;
            float w = Wh[((size_t)g << 20) + ((size_t)k << 10) + col];
            unsigned short hi = f2bf_rn(w);
            float r1 = w - bf2f(hi);          // exact
            unsigned short mi = f2bf_rn(r1);
            float r2 = r1 - bf2f(mi);         // exact
            unsigned short lo = f2bf_rn(r2);
            Whi[ck][j] = (short)hi;
            Wmi[ck][j] = (short)mi;
            Wlo[ck][j] = (short)lo;
        }
    }

    float creg = 0.f;   // cell state for (b=lane>>2, jl=lane&3); wave-0 lanes

    for (int t = 0; t < 256; ++t) {
        // prefetch this step's pre (barrier-independent -> overlaps the poll)
        float pr[4];
        if (wv == 0) {
            const float* pp = pre + ((size_t)t << 16) + ((size_t)(bc >> 2) << 10)
                              + (wg << 2) + (bc & 3);
#pragma unroll
            for (int r = 0; r < 4; ++r)
                pr[r] = pp[(size_t)((quad << 2) + r) << 12];
        }

        if (t > 0) {
            // all-wave lane-parallel poll: lane i watches flags[t-1][4i..4i+3]
            const int* fb = flags + ((t - 1) << 8) + (lane << 2);
            int f0 = 0, f1 = 0, f2 = 0, f3 = 0;
            int guard = 0;
            for (;;) {
                if (!f0) f0 = __hip_atomic_load(fb + 0, __ATOMIC_RELAXED,
                                                __HIP_MEMORY_SCOPE_AGENT);
                if (!f1) f1 = __hip_atomic_load(fb + 1, __ATOMIC_RELAXED,
                                                __HIP_MEMORY_SCOPE_AGENT);
                if (!f2) f2 = __hip_atomic_load(fb + 2, __ATOMIC_RELAXED,
                                                __HIP_MEMORY_SCOPE_AGENT);
                if (!f3) f3 = __hip_atomic_load(fb + 3, __ATOMIC_RELAXED,
                                                __HIP_MEMORY_SCOPE_AGENT);
                if (__all(f0 && f1 && f2 && f3)) break;
                __builtin_amdgcn_s_sleep(2);
                if (++guard > (1 << 13)) break;   // bounded: bug -> wrong answer
            }
            asm volatile("" ::: "memory");
        }

        f32x4 acc0 = {0.f, 0.f, 0.f, 0.f};
        f32x4 acc1 = {0.f, 0.f, 0.f, 0.f};
        if (t > 0) {
            const size_t pb = ((size_t)(t - 1) << 14) + ((size_t)bc << 10) + (wv << 8);
            const unsigned short* ph = hhi + pb;
            const unsigned short* pl = hlo + pb;
            bf16x8 ahi[8], alo[8];
#pragma unroll
            for (int ck = 0; ck < 8; ++ck) {
                ahi[ck] = *(const bf16x8*)(ph + (ck << 5) + (quad << 3));
                alo[ck] = *(const bf16x8*)(pl + (ck << 5) + (quad << 3));
            }
            // 5 split passes: hi*hi + hi*mid + hi*lo + lo*hi + lo*mid
#pragma unroll
            for (int ck = 0; ck < 8; ++ck) {
                if (ck & 1) {
                    acc1 = __builtin_amdgcn_mfma_f32_16x16x32_bf16(ahi[ck], Whi[ck], acc1, 0, 0, 0);
                    acc1 = __builtin_amdgcn_mfma_f32_16x16x32_bf16(ahi[ck], Wmi[ck], acc1, 0, 0, 0);
                    acc1 = __builtin_amdgcn_mfma_f32_16x16x32_bf16(ahi[ck], Wlo[ck], acc1, 0, 0, 0);
                    acc1 = __builtin_amdgcn_mfma_f32_16x16x32_bf16(alo[ck], Whi[ck], acc1, 0, 0, 0);
                    acc1 = __builtin_amdgcn_mfma_f32_16x16x32_bf16(alo[ck], Wmi[ck], acc1, 0, 0, 0);
                } else {
                    acc0 = __builtin_amdgcn_mfma_f32_16x16x32_bf16(ahi[ck], Whi[ck], acc0, 0, 0, 0);
                    acc0 = __builtin_amdgcn_mfma_f32_16x16x32_bf16(ahi[ck], Wmi[ck], acc0, 0, 0, 0);
                    acc0 = __builtin_amdgcn_mfma_f32_16x16x32_bf16(ahi[ck], Wlo[ck], acc0, 0, 0, 0);
                    acc0 = __builtin_amdgcn_mfma_f32_16x16x32_bf16(alo[ck], Whi[ck], acc0, 0, 0, 0);
                    acc0 = __builtin_amdgcn_mfma_f32_16x16x32_bf16(alo[ck], Wmi[ck], acc0, 0, 0, 0);
                }
            }
        }
        f32x4 acc = acc0 + acc1;
        *(f32x4*)&red[wv][lane][0] = acc;
        __syncthreads();

        if (wv == 0) {
            f32x4 s0 = *(const f32x4*)&red[0][lane][0];
            f32x4 s1 = *(const f32x4*)&red[1][lane][0];
            f32x4 s2 = *(const f32x4*)&red[2][lane][0];
            f32x4 s3 = *(const f32x4*)&red[3][lane][0];
            f32x4 s = (s0 + s1) + (s2 + s3);
            // C layout: col = lane&15 (=bc), row = quad*4 + r (=batch)
#pragma unroll
            for (int r = 0; r < 4; ++r)
                gsh[(quad << 2) + r][bc] = s[r] + pr[r];

            const int b2 = lane >> 2, jl2 = lane & 3;
            float fg = sigmoidf_(gsh[b2][jl2]);           // forget
            float ig = sigmoidf_(gsh[b2][4 + jl2]);       // input (percent)
            float pg = tanhf_(gsh[b2][8 + jl2]);          // input (potential)
            float og = sigmoidf_(gsh[b2][12 + jl2]);      // output (old h)
            creg = fg * creg + ig * pg;
            float h = tanhf_(creg) * og;

            const int j = (wg << 2) + jl2;
            unsigned short hh = f2bf_rn(h);
            unsigned short hl = f2bf_rn(h - bf2f(hh));
            size_t pidx = ((size_t)t << 14) + ((size_t)b2 << 10) + j;
            // agent-scope write-through stores: visible at the LLC, never
            // dirty in the producer's (non-coherent) XCD L2
            __hip_atomic_store(&hhi[pidx], hh, __ATOMIC_RELAXED, __HIP_MEMORY_SCOPE_AGENT);
            __hip_atomic_store(&hlo[pidx], hl, __ATOMIC_RELAXED, __HIP_MEMORY_SCOPE_AGENT);
            seq_out[((size_t)((b2 << 8) + t) << 10) + j] = h;   // next dispatch only
            if (is_last && t == 255) final_out[((size_t)b2 << 10) + j] = h;

            // drain ALL outstanding vmem (h stores reach the coherence point),
            // then fire-and-forget the per-producer flag: no atomic RTT on the
            // critical path.
            __builtin_amdgcn_s_waitcnt(0);
            asm volatile("" ::: "memory");
            if (lane == 0)
                __hip_atomic_store(&flags[(t << 8) + wg], 1, __ATOMIC_RELAXED,
                                   __HIP_MEMORY_SCOPE_AGENT);
        }
    }
}

// ---------------------------------------------------------------------------
extern "C" void kernel_launch(void* const* d_in, const int* in_sizes, int n_in,
                              void* d_out, int out_size, void* d_ws, size_t ws_size,
                              hipStream_t stream)
{
    (void)in_sizes; (void)n_in; (void)out_size; (void)ws_size;

    const float* x    = (const float*)d_in[0];   // [16][256][256]
    const float* Wh   = (const float*)d_in[1];   // [4][4][1024][1024]
    const float* Wx0  = (const float*)d_in[2];   // [4][256][1024]
    const float* Wx   = (const float*)d_in[3];   // [3][4][1024][1024]
    const float* bias = (const float*)d_in[4];   // [4][4][1024]

    float* pre  = (float*)d_ws;                    // 16,777,216 f
    float* seqA = pre + 16777216;                  // 4,194,304 f
    float* seqB = seqA + 4194304;                  // 4,194,304 f
    unsigned short* hhi = (unsigned short*)(seqB + 4194304);   // 4,194,304 u16
    unsigned short* hlo = hhi + 4194304;                       // 4,194,304 u16
    int* flags = (int*)(hlo + 4194304);            // 4 layers x 65536 ints
    const size_t FL_PER_LAYER = 256 * 256;

    float* fout = (float*)d_out;

    hipMemsetAsync(flags, 0, 4 * FL_PER_LAYER * sizeof(int), stream);

    const dim3 blk(256);
    const dim3 ggrid(32, 32);
    const size_t WLAYER = (size_t)4 * 1024 * 1024;

    for (int l = 0; l < 4; ++l) {
        const float* inp = (l == 0) ? x : ((l & 1) ? seqA : seqB);
        float* outp      = (l & 1) ? seqB : seqA;
        const float* wx  = (l == 0) ? Wx0 : (Wx + (size_t)(l - 1) * WLAYER);
        int K            = (l == 0) ? 256 : 1024;

        pre_gemm<<<ggrid, blk, 0, stream>>>(inp, wx, bias + (size_t)l * 4096, pre, K);

        const float* p = pre;
        const float* wh = Wh + (size_t)l * WLAYER;
        float* so = outp;
        unsigned short* phi = hhi;
        unsigned short* plo = hlo;
        int* fl = flags + (size_t)l * FL_PER_LAYER;
        int last = (l == 3);
        void* args[] = { (void*)&p, (void*)&wh, (void*)&so, (void*)&phi,
                         (void*)&plo, (void*)&fl, (void*)&fout, (void*)&last };
        hipLaunchCooperativeKernel((void*)lstm_scan, dim3(256), blk, args, 0, stream);
    }
}

// Round 6
// 6852.740 us; speedup vs baseline: 1.6977x; 1.6977x over previous
//
#include <hip/hip_runtime.h>

// B=16, T=256, IN=256, H=1024, L=4, 4 gates -> 4H=4096.
// R9 = R3 (twice-proven: 4x pre_gemm + 4x single-layer cooperative scan,
// identical MFMA numerics, identical register envelope, __launch_bounds__(256))
// with three serial-latency cuts:
//   1. counter tree flattened: producers fire-and-forget fetch_add on their
//      group's l1 line (NO old==15 readback RTT, NO root hop); wave-0 lanes
//      0-15 poll the 16 l1 lines in parallel with an __all ballot.
//   2. MFMA phase on 4 accumulators (chains 20 -> ~12).
//   3. seq_out store moved AFTER the flag (kernel-end release covers the next
//      dispatch), skipped on the last layer: pre-flag drain = 2 stores only.
// Spin bounded + dead-latch: protocol bug => fast wrong answer, never a hang.
//
// NOTE (hard-won): cooperative 256-wg launches on this stack silently fail to
// enqueue when the kernel's register footprint grows past the R3 envelope
// (R4/R5/R7/R8, 6-9 weight arrays, never ran). Keep total regs ~R3.
//
// ws (floats): pre 16,777,216 | seqA 4,194,304 | seqB 4,194,304
//              | hhi 4,194,304 u16 | hlo 4,194,304 u16
//              | ctr_l1 4 layers x 256 t x 16 grp x 32-stride ints (2MB)

typedef float f32x4 __attribute__((ext_vector_type(4)));
typedef short bf16x8 __attribute__((ext_vector_type(8)));

__device__ __forceinline__ unsigned short f2bf_rn(float x) {
    unsigned int u = __float_as_uint(x);
    u += 0x7FFFu + ((u >> 16) & 1u);          // round-to-nearest-even
    return (unsigned short)(u >> 16);
}
__device__ __forceinline__ float bf2f(unsigned short s) {
    return __uint_as_float(((unsigned int)s) << 16);
}
__device__ __forceinline__ float sigmoidf_(float x) { return 1.0f / (1.0f + __expf(-x)); }
__device__ __forceinline__ float tanhf_(float x) {
    float e = __expf(2.0f * x);
    return 1.0f - 2.0f / (e + 1.0f);
}

#define MFMA16(a, b, c) __builtin_amdgcn_mfma_f32_16x16x32_bf16((a), (b), (c), 0, 0, 0)

// ---------------------------------------------------------------------------
// pre[t][b][g*1024+j] = sum_k inp[b*T+t][k] * W[g][k][j] + bias[g*1024+j]
// fp32, 128x128 tile, BK=16, 256 threads, 8x8 micro-tile. (unchanged, proven)
// ---------------------------------------------------------------------------
__global__ __launch_bounds__(256)
void pre_gemm(const float* __restrict__ A, const float* __restrict__ W,
              const float* __restrict__ bias, float* __restrict__ out, int K)
{
    __shared__ float As[16][132];   // [k][m]
    __shared__ float Bs[16][132];   // [k][n]

    const int tid = threadIdx.x;
    const int m0 = blockIdx.y << 7;
    const int n0 = blockIdx.x << 7;
    const int g  = n0 >> 10;
    const int jb = n0 & 1023;
    const float* Wg = W + (size_t)g * K * 1024 + jb;

    const int tx = tid & 15;
    const int ty = tid >> 4;
    const int alk = tid & 15;
    const int alm = tid >> 4;
    const int bln = tid & 127;
    const int blkk = tid >> 7;

    float acc[8][8];
#pragma unroll
    for (int i = 0; i < 8; ++i)
#pragma unroll
        for (int j = 0; j < 8; ++j) acc[i][j] = 0.f;

    for (int k0 = 0; k0 < K; k0 += 16) {
        __syncthreads();
#pragma unroll
        for (int r = 0; r < 8; ++r) {
            int m = alm + (r << 4);
            As[alk][m] = A[(size_t)(m0 + m) * K + (k0 + alk)];
        }
#pragma unroll
        for (int r = 0; r < 8; ++r) {
            int kk = blkk + (r << 1);
            Bs[kk][bln] = Wg[(size_t)(k0 + kk) * 1024 + bln];
        }
        __syncthreads();
#pragma unroll
        for (int k = 0; k < 16; ++k) {
            float a[8], bb[8];
            *(f32x4*)&a[0]  = *(const f32x4*)&As[k][ty << 2];
            *(f32x4*)&a[4]  = *(const f32x4*)&As[k][64 + (ty << 2)];
            *(f32x4*)&bb[0] = *(const f32x4*)&Bs[k][tx << 2];
            *(f32x4*)&bb[4] = *(const f32x4*)&Bs[k][64 + (tx << 2)];
#pragma unroll
            for (int i = 0; i < 8; ++i)
#pragma unroll
                for (int j = 0; j < 8; ++j)
                    acc[i][j] = fmaf(a[i], bb[j], acc[i][j]);
        }
    }

    float bj[8];
#pragma unroll
    for (int j = 0; j < 8; ++j) {
        int nloc = (j < 4) ? ((tx << 2) + j) : (64 + (tx << 2) + (j - 4));
        bj[j] = bias[n0 + nloc];
    }
#pragma unroll
    for (int i = 0; i < 8; ++i) {
        int mloc = (i < 4) ? ((ty << 2) + i) : (64 + (ty << 2) + (i - 4));
        int m = m0 + mloc;
        int bidx = m >> 8;
        int tt   = m & 255;
        float* orow = out + ((size_t)((tt << 4) + bidx) << 12) + n0;
#pragma unroll
        for (int j = 0; j < 8; ++j) {
            int nloc = (j < 4) ? ((tx << 2) + j) : (64 + (tx << 2) + (j - 4));
            orow[nloc] = acc[i][j] + bj[j];
        }
    }
}

// ---------------------------------------------------------------------------
// Persistent cooperative LSTM scan, one layer. 256 wgs x 256 threads.
// Producer (wave 0): gates -> h stores (agent write-through) -> s_waitcnt(0)
// -> fire-and-forget fetch_add on l1[t][wg>>4] (no readback, no root).
// Watcher (wave 0, lanes 0-15): parallel poll of the 16 l1 lines, __all
// ballot; flag==16 per group ==> all producers' h at the coherence point.
// Consumer h reads use fresh per-t addresses -> no stale L1/L2 copies.
// ---------------------------------------------------------------------------
__global__ __launch_bounds__(256)
void lstm_scan(const float* __restrict__ pre,    // [T][B][4096]
               const float* __restrict__ Wh,     // [4][1024][1024] this layer
               float* __restrict__ seq_out,      // [B][T][1024]
               unsigned short* __restrict__ hhi, // [T][16][1024] bf16 hi plane
               unsigned short* __restrict__ hlo, // [T][16][1024] bf16 lo plane
               int* __restrict__ ctr_l1,         // [256 t][16 grp] stride-32
               float* __restrict__ final_out,    // [16][1024]
               int is_last)
{
    const int wg   = blockIdx.x;
    const int tid  = threadIdx.x;
    const int wv   = tid >> 6;        // wave 0..3 owns k-range [wv*256, +256)
    const int lane = tid & 63;
    const int bc   = lane & 15;       // A-frag m (=batch) / B-frag n (=gate col)
    const int quad = lane >> 4;

    __shared__ float red[4][64][4];   // cross-wave C reduction
    __shared__ float gsh[16][17];     // gate exchange [b][g*4+jl]

    // ---- one-time: load Wh slice, 3-term bf16 split into registers ----
    const int g   = bc >> 2;
    const int col = (wg << 2) + (bc & 3);
    bf16x8 Whi[8], Wmi[8], Wlo[8];
#pragma unroll
    for (int ck = 0; ck < 8; ++ck) {
#pragma unroll
        for (int j = 0; j < 8; ++j) {
            int k = (wv << 8) + (ck << 5) + (quad << 3) + j;
            float w = Wh[((size_t)g << 20) + ((size_t)k << 10) + col];
            unsigned short hi = f2bf_rn(w);
            float r1 = w - bf2f(hi);          // exact
            unsigned short mi = f2bf_rn(r1);
            float r2 = r1 - bf2f(mi);         // exact
            unsigned short lo = f2bf_rn(r2);
            Whi[ck][j] = (short)hi;
            Wmi[ck][j] = (short)mi;
            Wlo[ck][j] = (short)lo;
        }
    }

    float creg = 0.f;   // cell state for (b=lane>>2, jl=lane&3); wave-0 lanes
    int dead = 0;       // wave-0-uniform dead-latch for the bounded spin

    for (int t = 0; t < 256; ++t) {
        // prefetch this step's pre (barrier-independent -> overlaps the poll)
        float pr[4];
        if (wv == 0) {
            const float* pp = pre + ((size_t)t << 16) + ((size_t)(bc >> 2) << 10)
                              + (wg << 2) + (bc & 3);
#pragma unroll
            for (int r = 0; r < 4; ++r)
                pr[r] = pp[(size_t)((quad << 2) + r) << 12];
        }

        if (t > 0 && wv == 0 && !dead) {
            // lanes 0-15 each watch one of the 16 group counters for t-1
            const int* lb = ctr_l1 + (((t - 1) << 4) << 5);
            bool done = (lane >= 16);
            const int gi5 = (lane & 15) << 5;
            int guard = 0;
            for (;;) {
                if (!done)
                    done = __hip_atomic_load(lb + gi5, __ATOMIC_RELAXED,
                                             __HIP_MEMORY_SCOPE_AGENT) >= 16;
                if (__all(done)) break;
                __builtin_amdgcn_s_sleep(1);
                if (++guard > (1 << 15)) { dead = 1; break; }  // bug -> fast wrong answer
            }
        }
        __syncthreads();
        asm volatile("" ::: "memory");

        f32x4 a00 = {0.f, 0.f, 0.f, 0.f};
        f32x4 a01 = a00, a10 = a00, a11 = a00;   // 4 accs: shorter MFMA chains
        if (t > 0) {
            const size_t pb = ((size_t)(t - 1) << 14) + ((size_t)bc << 10) + (wv << 8);
            const unsigned short* ph = hhi + pb;
            const unsigned short* pl = hlo + pb;
            bf16x8 ahi[8], alo[8];
#pragma unroll
            for (int ck = 0; ck < 8; ++ck) {
                ahi[ck] = *(const bf16x8*)(ph + (ck << 5) + (quad << 3));
                alo[ck] = *(const bf16x8*)(pl + (ck << 5) + (quad << 3));
            }
            // 5 split passes: hi*hi + hi*mid + hi*lo + lo*hi + lo*mid
#pragma unroll
            for (int ck = 0; ck < 8; ++ck) {
                if (ck & 1) {
                    a10 = MFMA16(ahi[ck], Whi[ck], a10);
                    a11 = MFMA16(ahi[ck], Wmi[ck], a11);
                    a10 = MFMA16(ahi[ck], Wlo[ck], a10);
                    a11 = MFMA16(alo[ck], Whi[ck], a11);
                    a10 = MFMA16(alo[ck], Wmi[ck], a10);
                } else {
                    a00 = MFMA16(ahi[ck], Whi[ck], a00);
                    a01 = MFMA16(ahi[ck], Wmi[ck], a01);
                    a00 = MFMA16(ahi[ck], Wlo[ck], a00);
                    a01 = MFMA16(alo[ck], Whi[ck], a01);
                    a00 = MFMA16(alo[ck], Wmi[ck], a00);
                }
            }
        }
        f32x4 acc = (a00 + a01) + (a10 + a11);
        *(f32x4*)&red[wv][lane][0] = acc;
        __syncthreads();

        if (wv == 0) {
            f32x4 s0 = *(const f32x4*)&red[0][lane][0];
            f32x4 s1 = *(const f32x4*)&red[1][lane][0];
            f32x4 s2 = *(const f32x4*)&red[2][lane][0];
            f32x4 s3 = *(const f32x4*)&red[3][lane][0];
            f32x4 s = (s0 + s1) + (s2 + s3);
            // C layout: col = lane&15 (=bc), row = quad*4 + r (=batch)
#pragma unroll
            for (int r = 0; r < 4; ++r)
                gsh[(quad << 2) + r][bc] = s[r] + pr[r];

            const int b2 = lane >> 2, jl2 = lane & 3;
            float fg = sigmoidf_(gsh[b2][jl2]);           // forget
            float ig = sigmoidf_(gsh[b2][4 + jl2]);       // input (percent)
            float pg = tanhf_(gsh[b2][8 + jl2]);          // input (potential)
            float og = sigmoidf_(gsh[b2][12 + jl2]);      // output (old h)
            creg = fg * creg + ig * pg;
            float h = tanhf_(creg) * og;

            const int j = (wg << 2) + jl2;
            unsigned short hh = f2bf_rn(h);
            unsigned short hl = f2bf_rn(h - bf2f(hh));
            size_t pidx = ((size_t)t << 14) + ((size_t)b2 << 10) + j;
            // agent-scope write-through stores: visible at the LLC, never
            // dirty in the producer's (non-coherent) XCD L2
            __hip_atomic_store(&hhi[pidx], hh, __ATOMIC_RELAXED, __HIP_MEMORY_SCOPE_AGENT);
            __hip_atomic_store(&hlo[pidx], hl, __ATOMIC_RELAXED, __HIP_MEMORY_SCOPE_AGENT);
            if (is_last && t == 255) final_out[((size_t)b2 << 10) + j] = h;

            // drain the h stores to the coherence point, then fire-and-forget
            // the group counter (no readback, no root hop).
            __builtin_amdgcn_s_waitcnt(0);
            if (lane == 0)
                __hip_atomic_fetch_add(&ctr_l1[((t << 4) + (wg >> 4)) << 5], 1,
                                       __ATOMIC_RELAXED,
                                       __HIP_MEMORY_SCOPE_AGENT);

            // seq_out is consumed only by the NEXT dispatch (kernel-end
            // release) -> store it off the critical drain; skip on last layer.
            if (!is_last)
                seq_out[((size_t)((b2 << 8) + t) << 10) + j] = h;
        }
    }
}

// ---------------------------------------------------------------------------
extern "C" void kernel_launch(void* const* d_in, const int* in_sizes, int n_in,
                              void* d_out, int out_size, void* d_ws, size_t ws_size,
                              hipStream_t stream)
{
    (void)in_sizes; (void)n_in; (void)out_size; (void)ws_size;

    const float* x    = (const float*)d_in[0];   // [16][256][256]
    const float* Wh   = (const float*)d_in[1];   // [4][4][1024][1024]
    const float* Wx0  = (const float*)d_in[2];   // [4][256][1024]
    const float* Wx   = (const float*)d_in[3];   // [3][4][1024][1024]
    const float* bias = (const float*)d_in[4];   // [4][4][1024]

    float* pre  = (float*)d_ws;                    // 16,777,216 f
    float* seqA = pre + 16777216;                  // 4,194,304 f
    float* seqB = seqA + 4194304;                  // 4,194,304 f
    unsigned short* hhi = (unsigned short*)(seqB + 4194304);   // 4,194,304 u16
    unsigned short* hlo = hhi + 4194304;                       // 4,194,304 u16
    int* ctr = (int*)(hlo + 4194304);
    const size_t L1_PER_LAYER = 256 * 16 * 32;

    float* fout = (float*)d_out;

    hipMemsetAsync(ctr, 0, 4 * L1_PER_LAYER * sizeof(int), stream);

    const dim3 blk(256);
    const dim3 ggrid(32, 32);
    const size_t WLAYER = (size_t)4 * 1024 * 1024;

    for (int l = 0; l < 4; ++l) {
        const float* inp = (l == 0) ? x : ((l & 1) ? seqA : seqB);
        float* outp      = (l & 1) ? seqB : seqA;
        const float* wx  = (l == 0) ? Wx0 : (Wx + (size_t)(l - 1) * WLAYER);
        int K            = (l == 0) ? 256 : 1024;

        pre_gemm<<<ggrid, blk, 0, stream>>>(inp, wx, bias + (size_t)l * 4096, pre, K);

        const float* p = pre;
        const float* wh = Wh + (size_t)l * WLAYER;
        float* so = outp;
        unsigned short* phi = hhi;
        unsigned short* plo = hlo;
        int* pl1 = ctr + (size_t)l * L1_PER_LAYER;
        int last = (l == 3);
        void* args[] = { (void*)&p, (void*)&wh, (void*)&so, (void*)&phi,
                         (void*)&plo, (void*)&pl1, (void*)&fout, (void*)&last };
        hipLaunchCooperativeKernel((void*)lstm_scan, dim3(256), blk, args, 0, stream);
    }
}